// Round 3
// baseline (42208.783 us; speedup 1.0000x reference)
//
#include <hip/hip_runtime.h>
#include <cfloat>

#define NTRAIN 40000
#define NTEST  10000
#define DIM    512
#define NCOMP  64
#define KNN    32
#define KCAND  64   // approximate candidates kept per row, re-ranked with np-f32-emulated d2

#define M_TILE 32
#define N_TILE 256
#define K_CHUNK 16
#define BLOCK  256

// ---------------------------------------------------------------------------
// The harness reference ("ref=np") evaluates d2 in FLOAT32 via the matmul
// form. Its rounding flips ~1 boundary pair vs exact ranking (observed:
// f64-exact re-rank and f32-approx ranking both give the identical 0.123
// absmax). To match the reference we must REPRODUCE its f32 arithmetic:
//   trs_j = np.sum(x*x)    -> numpy scalar pairwise sum (128-blocks, 8 accs)
//   ts_i  = np.sum(t*t)    -> same
//   dot   = sgemm          -> sequential f32 FMA chain over k (BLAS
//                             micro-kernel: one FMA per k per C element)
//   d2    = f32( f32(ts + trs) - 2*dot )
// Ties (equal f32 d2) break by lowest train index, same as lax.top_k.
// fp contract(off) is required: HIP's default -ffp-contract=fast would fuse
// q*q into the adds and change rounding vs numpy's mul-then-add.
// ---------------------------------------------------------------------------

__device__ __forceinline__ float np_block128_sq(const float* __restrict__ q) {
#pragma clang fp contract(off)
    float r0 = q[0]*q[0], r1 = q[1]*q[1], r2 = q[2]*q[2], r3 = q[3]*q[3];
    float r4 = q[4]*q[4], r5 = q[5]*q[5], r6 = q[6]*q[6], r7 = q[7]*q[7];
    #pragma unroll
    for (int i = 8; i < 128; i += 8) {
        r0 += q[i+0]*q[i+0];
        r1 += q[i+1]*q[i+1];
        r2 += q[i+2]*q[i+2];
        r3 += q[i+3]*q[i+3];
        r4 += q[i+4]*q[i+4];
        r5 += q[i+5]*q[i+5];
        r6 += q[i+6]*q[i+6];
        r7 += q[i+7]*q[i+7];
    }
    return ((r0 + r1) + (r2 + r3)) + ((r4 + r5) + (r6 + r7));
}

// numpy pairwise_sum for n=512: (B(0:128)+B(128:256)) + (B(256:384)+B(384:512))
__device__ __forceinline__ float np_sq512(const float* __restrict__ q) {
#pragma clang fp contract(off)
    const float b0 = np_block128_sq(q);
    const float b1 = np_block128_sq(q + 128);
    const float b2 = np_block128_sq(q + 256);
    const float b3 = np_block128_sq(q + 384);
    return (b0 + b1) + (b2 + b3);
}

// BLAS sgemm-style dot: single accumulator, sequential k, FMA per element
__device__ __forceinline__ float np_dot512(const float* __restrict__ t,
                                           const float* __restrict__ x) {
    float acc = 0.f;
    for (int k = 0; k < DIM; k += 4) {
        const float4 tv = *(const float4*)(t + k);
        const float4 xv = *(const float4*)(x + k);
        acc = fmaf(tv.x, xv.x, acc);
        acc = fmaf(tv.y, xv.y, acc);
        acc = fmaf(tv.z, xv.z, acc);
        acc = fmaf(tv.w, xv.w, acc);
    }
    return acc;
}

__global__ __launch_bounds__(BLOCK, 2)
void knn_kernel(const float* __restrict__ train_x,
                const float* __restrict__ train_y,
                const float* __restrict__ test_x,
                float* __restrict__ out)
{
    __shared__ float As[K_CHUNK][M_TILE];       // 2 KB   (A chunk, [k][row])
    __shared__ float Bs[K_CHUNK][N_TILE];       // 16 KB  (B chunk, [k][col])
    __shared__ float Sc[M_TILE][N_TILE + 1];    // ~32 KB (tile scores; f32 S reuse in stage B)
    __shared__ float colSq[N_TILE];             // 1 KB   (train row sq-norms, approx)
    __shared__ float topD[M_TILE][KCAND];       // 8 KB   (reused as sel[] ints in stage B)
    __shared__ int   topI[M_TILE][KCAND];       // 8 KB

    const int tid    = threadIdx.x;
    const int m_base = blockIdx.x * M_TILE;
    const int tx     = tid & 31;   // col group: cols tx*8 .. tx*8+7
    const int ty     = tid >> 5;   // row group: rows ty*4 .. ty*4+3

    // init candidate lists
    for (int i = tid; i < M_TILE * KCAND; i += BLOCK) {
        (&topD[0][0])[i] = FLT_MAX;
        (&topI[0][0])[i] = 0;
    }

    float rowMax = FLT_MAX;  // running 64th-smallest; only meaningful for tid < M_TILE

    // A-chunk load assignment (threads 0..127): 32 rows x 4 float4's per chunk
    const int a_row  = tid >> 2;
    const int a_k    = (tid & 3) * 4;
    const int a_grow = (m_base + a_row < NTEST) ? (m_base + a_row) : (NTEST - 1);

    // ---------------- Stage A: approximate scores + top-64 candidates ----------------
    for (int n_base = 0; n_base < NTRAIN; n_base += N_TILE) {
        float acc[4][8];
        #pragma unroll
        for (int i = 0; i < 4; ++i)
            #pragma unroll
            for (int j = 0; j < 8; ++j) acc[i][j] = 0.f;

        int b_row = n_base + tid;
        if (b_row >= NTRAIN) b_row = NTRAIN - 1;
        const float* bp = train_x + (size_t)b_row * DIM;
        float sq_acc = 0.f;  // approx ||train_{b_row}||^2, built during staging

        for (int k_base = 0; k_base < DIM; k_base += K_CHUNK) {
            __syncthreads();  // previous consumers of As/Bs (or Sc scan) done
            if (tid < 128) {
                const float4 v = *(const float4*)(test_x + (size_t)a_grow * DIM + k_base + a_k);
                As[a_k + 0][a_row] = v.x;
                As[a_k + 1][a_row] = v.y;
                As[a_k + 2][a_row] = v.z;
                As[a_k + 3][a_row] = v.w;
            }
            {
                const float4* tp = (const float4*)(bp + k_base);
                const float4 v0 = tp[0], v1 = tp[1], v2 = tp[2], v3 = tp[3];
                Bs[0][tid]  = v0.x; Bs[1][tid]  = v0.y; Bs[2][tid]  = v0.z; Bs[3][tid]  = v0.w;
                Bs[4][tid]  = v1.x; Bs[5][tid]  = v1.y; Bs[6][tid]  = v1.z; Bs[7][tid]  = v1.w;
                Bs[8][tid]  = v2.x; Bs[9][tid]  = v2.y; Bs[10][tid] = v2.z; Bs[11][tid] = v2.w;
                Bs[12][tid] = v3.x; Bs[13][tid] = v3.y; Bs[14][tid] = v3.z; Bs[15][tid] = v3.w;
                sq_acc += v0.x*v0.x + v0.y*v0.y + v0.z*v0.z + v0.w*v0.w
                        + v1.x*v1.x + v1.y*v1.y + v1.z*v1.z + v1.w*v1.w
                        + v2.x*v2.x + v2.y*v2.y + v2.z*v2.z + v2.w*v2.w
                        + v3.x*v3.x + v3.y*v3.y + v3.z*v3.z + v3.w*v3.w;
            }
            __syncthreads();
            #pragma unroll
            for (int k = 0; k < K_CHUNK; ++k) {
                const float4 av  = *(const float4*)&As[k][ty * 4];
                const float4 bv0 = *(const float4*)&Bs[k][tx * 8];
                const float4 bv1 = *(const float4*)&Bs[k][tx * 8 + 4];
                const float a[4] = {av.x, av.y, av.z, av.w};
                const float b[8] = {bv0.x, bv0.y, bv0.z, bv0.w,
                                    bv1.x, bv1.y, bv1.z, bv1.w};
                #pragma unroll
                for (int i = 0; i < 4; ++i)
                    #pragma unroll
                    for (int j = 0; j < 8; ++j)
                        acc[i][j] = fmaf(a[i], b[j], acc[i][j]);
            }
        }

        // publish this tile's train sq-norms
        colSq[tid] = sq_acc;
        __syncthreads();

        // scores -> LDS (OOB cols get +inf so they never get selected)
        #pragma unroll
        for (int i = 0; i < 4; ++i) {
            #pragma unroll
            for (int j = 0; j < 8; ++j) {
                const int c    = tx * 8 + j;
                const int gcol = n_base + c;
                const float s  = (gcol < NTRAIN) ? (colSq[c] - 2.f * acc[i][j]) : FLT_MAX;
                Sc[ty * 4 + i][c] = s;
            }
        }
        __syncthreads();

        // streaming top-64 update: one thread per test row
        if (tid < M_TILE) {
            float rmax = rowMax;
            for (int c = 0; c < N_TILE; ++c) {
                const float s = Sc[tid][c];
                if (s < rmax) {
                    // evict current max; among equal maxes evict the LARGEST index
                    int bi = 0; float bv = topD[tid][0]; int bidx = topI[tid][0];
                    #pragma unroll
                    for (int i = 1; i < KCAND; ++i) {
                        const float v  = topD[tid][i];
                        const int   id = topI[tid][i];
                        if (v > bv || (v == bv && id > bidx)) { bv = v; bi = i; bidx = id; }
                    }
                    topD[tid][bi] = s;
                    topI[tid][bi] = n_base + c;
                    float nm = -FLT_MAX;
                    #pragma unroll
                    for (int i = 0; i < KCAND; ++i) nm = fmaxf(nm, topD[tid][i]);
                    rmax = nm;
                }
            }
            rowMax = rmax;
        }
        __syncthreads();
    }

    // ---------------- Stage B: np-f32-emulated d2 for the 64 candidates ----------------
    float* Sf = &Sc[0][0];   // reuse Sc storage as [M_TILE][KCAND] f32, flat
    {
#pragma clang fp contract(off)
        const int r  = tid >> 3;       // row 0..31
        const int j0 = tid & 7;        // candidate lane 0..7
        int grow = m_base + r; if (grow >= NTEST) grow = NTEST - 1;
        const float* tp = test_x + (size_t)grow * DIM;
        const float ts = np_sq512(tp);
        for (int jj = j0; jj < KCAND; jj += 8) {
            const int idx = topI[r][jj];
            const float* xp = train_x + (size_t)idx * DIM;
            const float trs = np_sq512(xp);
            const float dt  = np_dot512(tp, xp);
            const float T   = ts + trs;        // f32 round (test_sq + train_sq)
            const float w   = 2.0f * dt;       // exact
            Sf[r * KCAND + jj] = T - w;        // f32 round, no FMA contraction
        }
    }
    __syncthreads();

    // selection: thread r picks top-32 (smallest d2, tie -> lowest train index),
    // identical ordering semantics to lax.top_k(-d2) / stable argsort
    int* sel = (int*)&topD[0][0];  // topD storage no longer needed
    if (tid < M_TILE) {
        const int r = tid;
        unsigned long long used = 0ULL;
        for (int p = 0; p < KNN; ++p) {
            float bv = FLT_MAX; int bj = 0; int bidx = 0x7fffffff;
            for (int j = 0; j < KCAND; ++j) {
                if (used & (1ULL << j)) continue;
                const float v = Sf[r * KCAND + j];
                const int  id = topI[r][j];
                if (v < bv || (v == bv && id < bidx)) { bv = v; bj = j; bidx = id; }
            }
            used |= (1ULL << bj);
            sel[r * KNN + p] = bidx;
        }
    }
    __syncthreads();

    // epilogue: mean of the 32 selected neighbors' labels
    const int r    = tid >> 3;
    const int c0   = (tid & 7) * 8;
    const int grow = m_base + r;
    if (grow < NTEST) {
        float s0=0,s1=0,s2=0,s3=0,s4=0,s5=0,s6=0,s7=0;
        for (int n = 0; n < KNN; ++n) {
            const float* yp = train_y + (size_t)sel[r * KNN + n] * NCOMP + c0;
            const float4 y0 = *(const float4*)yp;
            const float4 y1 = *(const float4*)(yp + 4);
            s0 += y0.x; s1 += y0.y; s2 += y0.z; s3 += y0.w;
            s4 += y1.x; s5 += y1.y; s6 += y1.z; s7 += y1.w;
        }
        const float inv = 1.0f / KNN;
        float* op = out + (size_t)grow * NCOMP + c0;
        *(float4*)op       = make_float4(s0*inv, s1*inv, s2*inv, s3*inv);
        *(float4*)(op + 4) = make_float4(s4*inv, s5*inv, s6*inv, s7*inv);
    }
}

extern "C" void kernel_launch(void* const* d_in, const int* in_sizes, int n_in,
                              void* d_out, int out_size, void* d_ws, size_t ws_size,
                              hipStream_t stream) {
    const float* train_x = (const float*)d_in[0];
    const float* train_y = (const float*)d_in[1];
    const float* test_x  = (const float*)d_in[2];
    float* out = (float*)d_out;

    const int grid = (NTEST + M_TILE - 1) / M_TILE;  // 313
    knn_kernel<<<grid, BLOCK, 0, stream>>>(train_x, train_y, test_x, out);
}

// Round 4
// 2466.521 us; speedup vs baseline: 17.1127x; 17.1127x over previous
//
#include <hip/hip_runtime.h>
#include <cfloat>

#define NTRAIN 40000
#define NTEST  10000
#define DIM    512
#define NCOMP  64
#define KNN    32

// ---------------- stage-A geometry ----------------
#define NSEG   8
#define SEGC   (NTRAIN / NSEG)          // 5000 train cols per segment
#define BM     128
#define BN     128
#define BK     64
#define NTILES ((SEGC + BN - 1) / BN)   // 40 (last tile: 8 valid cols)
#define MTILES ((NTEST + BM - 1) / BM)  // 79
#define LSEL   12                        // per-bucket top-list length
#define CPS    (4 * LSEL)                // 48 candidates per (row, segment)
#define KCAND  48                        // candidates re-ranked exactly per row

typedef __bf16 bf16x8 __attribute__((ext_vector_type(8)));
typedef float  f32x4  __attribute__((ext_vector_type(4)));
typedef unsigned short u16x8 __attribute__((ext_vector_type(8)));

// ---------------- workspace layout (bytes) ----------------
#define OFF_TRAINBF 0ULL                                   // 40000*512*2 = 40,960,000
#define OFF_TESTBF  40960000ULL                            // 10000*512*2 = 10,240,000
#define OFF_TRS     51200000ULL                            // 40000*4
#define OFF_NPTRS   51360000ULL                            // 40000*4
#define OFF_NPTESTS 51520000ULL                            // 10000*4
#define OFF_CAND    51560448ULL                            // 10000*8*48*8 = 30,720,000
#define OFF_CUT     82280448ULL                            // 10000*48*4 = 1,920,000
#define OFF_D2      84200448ULL                            // 10000*48*4 = 1,920,000
#define WS_NEED     86120448ULL

// ---------------------------------------------------------------------------
// np-f32 emulation of the harness reference (verified passing in round 3):
//   norms = numpy pairwise sum (128-blocks, 8 accumulators)
//   dot   = sequential f32 FMA chain (BLAS microkernel accumulation order)
//   d2    = f32( f32(ts + trs) - 2*dot ), no FMA contraction
// ---------------------------------------------------------------------------
__device__ __forceinline__ float np_block128_sq(const float* __restrict__ q) {
#pragma clang fp contract(off)
    float r0 = q[0]*q[0], r1 = q[1]*q[1], r2 = q[2]*q[2], r3 = q[3]*q[3];
    float r4 = q[4]*q[4], r5 = q[5]*q[5], r6 = q[6]*q[6], r7 = q[7]*q[7];
    #pragma unroll
    for (int i = 8; i < 128; i += 8) {
        r0 += q[i+0]*q[i+0];
        r1 += q[i+1]*q[i+1];
        r2 += q[i+2]*q[i+2];
        r3 += q[i+3]*q[i+3];
        r4 += q[i+4]*q[i+4];
        r5 += q[i+5]*q[i+5];
        r6 += q[i+6]*q[i+6];
        r7 += q[i+7]*q[i+7];
    }
    return ((r0 + r1) + (r2 + r3)) + ((r4 + r5) + (r6 + r7));
}

__device__ __forceinline__ float np_sq512(const float* __restrict__ q) {
#pragma clang fp contract(off)
    const float b0 = np_block128_sq(q);
    const float b1 = np_block128_sq(q + 128);
    const float b2 = np_block128_sq(q + 256);
    const float b3 = np_block128_sq(q + 384);
    return (b0 + b1) + (b2 + b3);
}

__device__ __forceinline__ float np_dot512(const float* __restrict__ t,
                                           const float* __restrict__ x) {
    float acc = 0.f;
    for (int k = 0; k < DIM; k += 4) {
        const float4 tv = *(const float4*)(t + k);
        const float4 xv = *(const float4*)(x + k);
        acc = fmaf(tv.x, xv.x, acc);
        acc = fmaf(tv.y, xv.y, acc);
        acc = fmaf(tv.z, xv.z, acc);
        acc = fmaf(tv.w, xv.w, acc);
    }
    return acc;
}

__device__ __forceinline__ unsigned short f32_to_bf16_rne(float f) {
    unsigned int u = __float_as_uint(f);
    u += 0x7fffu + ((u >> 16) & 1u);
    return (unsigned short)(u >> 16);
}

__device__ __forceinline__ void global_load_lds16(const void* g, void* l) {
    __builtin_amdgcn_global_load_lds(
        (const __attribute__((address_space(1))) void*)g,
        (__attribute__((address_space(3))) void*)l, 16, 0, 0);
}

// ======================= K0a: f32 -> bf16 + approx train norms =======================
__global__ void prep_convert(const float* __restrict__ train_x,
                             const float* __restrict__ test_x,
                             unsigned short* __restrict__ train_bf,
                             unsigned short* __restrict__ test_bf,
                             float* __restrict__ trs)
{
    const int wid = threadIdx.x >> 6, lane = threadIdx.x & 63;
    const int row = blockIdx.x * 4 + wid;              // 0..49999
    if (row >= NTRAIN + NTEST) return;
    const bool is_train = row < NTRAIN;
    const float* src = is_train ? (train_x + (size_t)row * DIM)
                                : (test_x + (size_t)(row - NTRAIN) * DIM);
    unsigned short* dst = is_train ? (train_bf + (size_t)row * DIM)
                                   : (test_bf + (size_t)(row - NTRAIN) * DIM);
    const float4 v0 = *(const float4*)(src + lane * 8);
    const float4 v1 = *(const float4*)(src + lane * 8 + 4);
    const float f[8] = {v0.x, v0.y, v0.z, v0.w, v1.x, v1.y, v1.z, v1.w};
    u16x8 o;
    float ss = 0.f;
    #pragma unroll
    for (int j = 0; j < 8; ++j) {
        o[j] = f32_to_bf16_rne(f[j]);
        ss += f[j] * f[j];
    }
    *(u16x8*)(dst + lane * 8) = o;
    if (is_train) {
        #pragma unroll
        for (int d = 1; d < 64; d <<= 1) ss += __shfl_xor(ss, d);
        if (lane == 0) trs[row] = ss;
    }
}

// ======================= K0b: exact np norms =======================
__global__ void prep_npnorm(const float* __restrict__ train_x,
                            const float* __restrict__ test_x,
                            float* __restrict__ np_trs,
                            float* __restrict__ np_tests)
{
    const int t = blockIdx.x * 256 + threadIdx.x;
    if (t < NTRAIN)                np_trs[t] = np_sq512(train_x + (size_t)t * DIM);
    else if (t < NTRAIN + NTEST)   np_tests[t - NTRAIN] = np_sq512(test_x + (size_t)(t - NTRAIN) * DIM);
}

// ======================= K1: MFMA candidate generation =======================
// 128x128 score tile per WG, 4 waves (2x2 of 64x64), BK=64, K=512.
// LDS tiles [row][8 granules-of-8-bf16], granule swizzled g' = g ^ (row&7)
// (conflict-free-ish ds_read_b128; global_load_lds dest is linear, source
//  address carries the inverse swizzle).
// Per-thread register top-12 lists, bucket = (row, col-quarter); 48 cand/(row,seg).
__device__ __forceinline__ void scan_insert(float s, int gidx,
                                            float (&sc)[LSEL], int (&id)[LSEL]) {
    if (s < sc[LSEL - 1]) {
        #pragma unroll
        for (int i = LSEL - 1; i >= 1; --i) {
            const bool up = (s < sc[i - 1]);
            const float ns = up ? sc[i - 1] : s;
            const int   ni = up ? id[i - 1] : gidx;
            if (s < sc[i]) { sc[i] = ns; id[i] = ni; }
        }
        if (s < sc[0]) { sc[0] = s; id[0] = gidx; }
    }
}

__global__ __launch_bounds__(256, 2)
void stageA(const unsigned short* __restrict__ train_bf,
            const unsigned short* __restrict__ test_bf,
            const float* __restrict__ trs,
            float2* __restrict__ cand)
{
    __shared__ unsigned short Ab[BM * BK];   // 16 KB
    __shared__ unsigned short Bb[BN * BK];   // 16 KB
    __shared__ float Sc[64 * 129];           // 33 KB (half-tile scores, +1 pad)

    const int tid  = threadIdx.x;
    const int wid  = tid >> 6;
    const int lane = tid & 63;
    const int l15 = lane & 15, l4 = lane >> 4, l7 = lane & 7;
    const int wr = wid >> 1, wc = wid & 1;

    const int m   = blockIdx.x % MTILES;
    const int seg = blockIdx.x / MTILES;
    const int m_base = m * BM;
    const int seg0   = seg * SEGC;

    const int srow = tid >> 2;   // scan row within half (0..63)
    const int q    = tid & 3;    // col quarter

    float sc0[LSEL], sc1[LSEL];
    int   id0[LSEL], id1[LSEL];
    #pragma unroll
    for (int i = 0; i < LSEL; ++i) { sc0[i] = FLT_MAX; sc1[i] = FLT_MAX; id0[i] = 0; id1[i] = 0; }

    for (int tile = 0; tile < NTILES; ++tile) {
        const int n_base = tile * BN;

        f32x4 acc[4][4];
        #pragma unroll
        for (int i = 0; i < 4; ++i)
            #pragma unroll
            for (int j = 0; j < 4; ++j) acc[i][j] = (f32x4){0.f, 0.f, 0.f, 0.f};

        for (int kc = 0; kc < DIM / BK; ++kc) {
            const int k_base = kc * BK;
            __syncthreads();                      // previous LDS consumers done
            #pragma unroll
            for (int i = 0; i < 4; ++i) {        // A: 1024 granules, wave quarter
                const int d   = wid * 256 + i * 64 + lane;
                const int row = d >> 3;
                const int g   = (d & 7) ^ (row & 7);
                int grow = m_base + row; if (grow > NTEST - 1) grow = NTEST - 1;
                global_load_lds16(test_bf + (size_t)grow * DIM + k_base + g * 8,
                                  &Ab[(wid * 256 + i * 64) * 8]);
            }
            #pragma unroll
            for (int i = 0; i < 4; ++i) {        // B: 1024 granules
                const int d   = wid * 256 + i * 64 + lane;
                const int row = d >> 3;
                const int g   = (d & 7) ^ (row & 7);
                int cis = n_base + row; if (cis > SEGC - 1) cis = SEGC - 1;
                global_load_lds16(train_bf + (size_t)(seg0 + cis) * DIM + k_base + g * 8,
                                  &Bb[(wid * 256 + i * 64) * 8]);
            }
            __syncthreads();                      // vmcnt(0) drain + barrier
            #pragma unroll
            for (int h = 0; h < 2; ++h) {        // two K=32 halves
                bf16x8 aF[4], bF[4];
                #pragma unroll
                for (int i = 0; i < 4; ++i) {
                    const int arow = wr * 64 + 16 * i + l15;
                    aF[i] = *(const bf16x8*)&Ab[(arow * 8 + ((h * 4 + l4) ^ l7)) * 8];
                    const int brow = wc * 64 + 16 * i + l15;
                    bF[i] = *(const bf16x8*)&Bb[(brow * 8 + ((h * 4 + l4) ^ l7)) * 8];
                }
                #pragma unroll
                for (int i = 0; i < 4; ++i)
                    #pragma unroll
                    for (int j = 0; j < 4; ++j)
                        acc[i][j] = __builtin_amdgcn_mfma_f32_16x16x32_bf16(
                            aF[i], bF[j], acc[i][j], 0, 0, 0);
            }
        }

        // -------- selection: two half-tiles through Sc --------
        // phase 0: rows 0..63 (written by waves wr==0)
        __syncthreads();
        if (wr == 0) {
            #pragma unroll
            for (int j = 0; j < 4; ++j) {
                const int c   = wc * 64 + 16 * j + l15;
                const int cis = n_base + c;
                const bool valid = cis < SEGC;
                const float t = valid ? trs[seg0 + cis] : 0.f;
                #pragma unroll
                for (int i = 0; i < 4; ++i) {
                    #pragma unroll
                    for (int r = 0; r < 4; ++r) {
                        const int rih = 16 * i + l4 * 4 + r;
                        Sc[rih * 129 + c] = valid ? fmaf(-2.f, acc[i][j][r], t) : FLT_MAX;
                    }
                }
            }
        }
        __syncthreads();
        {
            const int gbase = seg0 + n_base;
            #pragma unroll
            for (int j = 0; j < 32; ++j) {
                const int c = q * 32 + ((j + 8 * q) & 31);   // quarter-rotated scan
                scan_insert(Sc[srow * 129 + c], gbase + c, sc0, id0);
            }
        }
        __syncthreads();
        // phase 1: rows 64..127 (written by waves wr==1)
        if (wr == 1) {
            #pragma unroll
            for (int j = 0; j < 4; ++j) {
                const int c   = wc * 64 + 16 * j + l15;
                const int cis = n_base + c;
                const bool valid = cis < SEGC;
                const float t = valid ? trs[seg0 + cis] : 0.f;
                #pragma unroll
                for (int i = 0; i < 4; ++i) {
                    #pragma unroll
                    for (int r = 0; r < 4; ++r) {
                        const int rih = 16 * i + l4 * 4 + r;
                        Sc[rih * 129 + c] = valid ? fmaf(-2.f, acc[i][j][r], t) : FLT_MAX;
                    }
                }
            }
        }
        __syncthreads();
        {
            const int gbase = seg0 + n_base;
            #pragma unroll
            for (int j = 0; j < 32; ++j) {
                const int c = q * 32 + ((j + 8 * q) & 31);
                scan_insert(Sc[srow * 129 + c], gbase + c, sc1, id1);
            }
        }
    }

    // -------- dump candidates --------
    {
        const int r0 = m_base + srow;
        if (r0 < NTEST) {
            float2* d = cand + ((size_t)r0 * NSEG + seg) * CPS + q * LSEL;
            #pragma unroll
            for (int k = 0; k < LSEL; ++k) d[k] = make_float2(sc0[k], __int_as_float(id0[k]));
        }
        const int r1 = m_base + 64 + srow;
        if (r1 < NTEST) {
            float2* d = cand + ((size_t)r1 * NSEG + seg) * CPS + q * LSEL;
            #pragma unroll
            for (int k = 0; k < LSEL; ++k) d[k] = make_float2(sc1[k], __int_as_float(id1[k]));
        }
    }
}

// ======================= K2: cut 384 -> 48 by approx score =======================
__global__ void cut48(const float2* __restrict__ cand, int* __restrict__ cut)
{
    __shared__ float2 C[4][NSEG * CPS];          // 4 x 384 x 8B = 12 KB
    const int wid = threadIdx.x >> 6, lane = threadIdx.x & 63;
    const int row = blockIdx.x * 4 + wid;        // grid*4 == NTEST exactly
    const float2* src = cand + (size_t)row * (NSEG * CPS);
    #pragma unroll
    for (int t = 0; t < 6; ++t) C[wid][lane + t * 64] = src[lane + t * 64];
    __syncthreads();
    #pragma unroll
    for (int t = 0; t < 6; ++t) {
        const float2 mine = C[wid][lane + t * 64];
        const float ms = mine.x; const int mi = __float_as_int(mine.y);
        int rank = 0;
        for (int o = 0; o < NSEG * CPS; ++o) {
            const float2 ot = C[wid][o];
            const float os = ot.x; const int oi = __float_as_int(ot.y);
            rank += (os < ms || (os == ms && oi < mi)) ? 1 : 0;
        }
        if (rank < KCAND) cut[(size_t)row * KCAND + rank] = mi;
    }
}

// ======================= K3: exact np-f32 d2 for 48 candidates =======================
__global__ void npd2_kernel(const float* __restrict__ train_x,
                            const float* __restrict__ test_x,
                            const float* __restrict__ np_trs,
                            const float* __restrict__ np_tests,
                            const int* __restrict__ cut,
                            float* __restrict__ d2)
{
#pragma clang fp contract(off)
    const int T = blockIdx.x * 256 + threadIdx.x;
    if (T >= NTEST * KCAND) return;
    const int row = T / KCAND;
    const int idx = cut[T];
    const float dt = np_dot512(test_x + (size_t)row * DIM, train_x + (size_t)idx * DIM);
    const float Tv = np_tests[row] + np_trs[idx];   // f32 round
    const float w  = 2.0f * dt;                     // exact
    d2[T] = Tv - w;                                 // f32 round, no contraction
}

// ======================= K4: top-32 select + label mean =======================
__global__ void select_out(const float* __restrict__ train_y,
                           const int* __restrict__ cut,
                           const float* __restrict__ d2,
                           float* __restrict__ out)
{
    __shared__ float D[4][KCAND];
    __shared__ int   I[4][KCAND];
    __shared__ int   S[4][KNN];
    const int wid = threadIdx.x >> 6, lane = threadIdx.x & 63;
    const int row = blockIdx.x * 4 + wid;        // grid*4 == NTEST exactly
    if (lane < KCAND) {
        D[wid][lane] = d2[(size_t)row * KCAND + lane];
        I[wid][lane] = cut[(size_t)row * KCAND + lane];
    }
    __syncthreads();
    if (lane < KCAND) {
        const float ms = D[wid][lane]; const int mi = I[wid][lane];
        int rank = 0;
        #pragma unroll
        for (int o = 0; o < KCAND; ++o)
            rank += (D[wid][o] < ms || (D[wid][o] == ms && I[wid][o] < mi)) ? 1 : 0;
        if (rank < KNN) S[wid][rank] = mi;       // (dist, idx) order == lax.top_k
    }
    __syncthreads();
    float s = 0.f;
    #pragma unroll
    for (int n = 0; n < KNN; ++n)
        s += train_y[(size_t)S[wid][n] * NCOMP + lane];
    out[(size_t)row * NCOMP + lane] = s * (1.0f / KNN);
}

// ======================= fallback: round-3 monolithic kernel =======================
#define FM_TILE 32
#define FN_TILE 256
#define FK_CHUNK 16
__global__ __launch_bounds__(256, 2)
void knn_fallback(const float* __restrict__ train_x,
                  const float* __restrict__ train_y,
                  const float* __restrict__ test_x,
                  float* __restrict__ out)
{
    __shared__ float As[FK_CHUNK][FM_TILE];
    __shared__ float Bs[FK_CHUNK][FN_TILE];
    __shared__ float Scb[FM_TILE][FN_TILE + 1];
    __shared__ float colSq[FN_TILE];
    __shared__ float topD[FM_TILE][64];
    __shared__ int   topI[FM_TILE][64];

    const int tid    = threadIdx.x;
    const int m_base = blockIdx.x * FM_TILE;
    const int tx     = tid & 31;
    const int ty     = tid >> 5;

    for (int i = tid; i < FM_TILE * 64; i += 256) {
        (&topD[0][0])[i] = FLT_MAX;
        (&topI[0][0])[i] = 0;
    }
    float rowMax = FLT_MAX;
    const int a_row  = tid >> 2;
    const int a_k    = (tid & 3) * 4;
    const int a_grow = (m_base + a_row < NTEST) ? (m_base + a_row) : (NTEST - 1);

    for (int n_base = 0; n_base < NTRAIN; n_base += FN_TILE) {
        float accf[4][8];
        #pragma unroll
        for (int i = 0; i < 4; ++i)
            #pragma unroll
            for (int j = 0; j < 8; ++j) accf[i][j] = 0.f;
        int b_row = n_base + tid;
        if (b_row >= NTRAIN) b_row = NTRAIN - 1;
        const float* bp = train_x + (size_t)b_row * DIM;
        float sq_acc = 0.f;
        for (int k_base = 0; k_base < DIM; k_base += FK_CHUNK) {
            __syncthreads();
            if (tid < 128) {
                const float4 v = *(const float4*)(test_x + (size_t)a_grow * DIM + k_base + a_k);
                As[a_k + 0][a_row] = v.x; As[a_k + 1][a_row] = v.y;
                As[a_k + 2][a_row] = v.z; As[a_k + 3][a_row] = v.w;
            }
            {
                const float4* tp = (const float4*)(bp + k_base);
                const float4 v0 = tp[0], v1 = tp[1], v2 = tp[2], v3 = tp[3];
                Bs[0][tid]=v0.x; Bs[1][tid]=v0.y; Bs[2][tid]=v0.z; Bs[3][tid]=v0.w;
                Bs[4][tid]=v1.x; Bs[5][tid]=v1.y; Bs[6][tid]=v1.z; Bs[7][tid]=v1.w;
                Bs[8][tid]=v2.x; Bs[9][tid]=v2.y; Bs[10][tid]=v2.z; Bs[11][tid]=v2.w;
                Bs[12][tid]=v3.x; Bs[13][tid]=v3.y; Bs[14][tid]=v3.z; Bs[15][tid]=v3.w;
                sq_acc += v0.x*v0.x+v0.y*v0.y+v0.z*v0.z+v0.w*v0.w
                        + v1.x*v1.x+v1.y*v1.y+v1.z*v1.z+v1.w*v1.w
                        + v2.x*v2.x+v2.y*v2.y+v2.z*v2.z+v2.w*v2.w
                        + v3.x*v3.x+v3.y*v3.y+v3.z*v3.z+v3.w*v3.w;
            }
            __syncthreads();
            #pragma unroll
            for (int k = 0; k < FK_CHUNK; ++k) {
                const float4 av  = *(const float4*)&As[k][ty * 4];
                const float4 bv0 = *(const float4*)&Bs[k][tx * 8];
                const float4 bv1 = *(const float4*)&Bs[k][tx * 8 + 4];
                const float a[4] = {av.x, av.y, av.z, av.w};
                const float b[8] = {bv0.x, bv0.y, bv0.z, bv0.w, bv1.x, bv1.y, bv1.z, bv1.w};
                #pragma unroll
                for (int i = 0; i < 4; ++i)
                    #pragma unroll
                    for (int j = 0; j < 8; ++j)
                        accf[i][j] = fmaf(a[i], b[j], accf[i][j]);
            }
        }
        colSq[tid] = sq_acc;
        __syncthreads();
        #pragma unroll
        for (int i = 0; i < 4; ++i)
            #pragma unroll
            for (int j = 0; j < 8; ++j) {
                const int c = tx * 8 + j;
                const int gcol = n_base + c;
                Scb[ty * 4 + i][c] = (gcol < NTRAIN) ? (colSq[c] - 2.f * accf[i][j]) : FLT_MAX;
            }
        __syncthreads();
        if (tid < FM_TILE) {
            float rmax = rowMax;
            for (int c = 0; c < FN_TILE; ++c) {
                const float s = Scb[tid][c];
                if (s < rmax) {
                    int bi = 0; float bv = topD[tid][0]; int bidx = topI[tid][0];
                    #pragma unroll
                    for (int i = 1; i < 64; ++i) {
                        const float v = topD[tid][i]; const int idv = topI[tid][i];
                        if (v > bv || (v == bv && idv > bidx)) { bv = v; bi = i; bidx = idv; }
                    }
                    topD[tid][bi] = s; topI[tid][bi] = n_base + c;
                    float nm = -FLT_MAX;
                    #pragma unroll
                    for (int i = 0; i < 64; ++i) nm = fmaxf(nm, topD[tid][i]);
                    rmax = nm;
                }
            }
            rowMax = rmax;
        }
        __syncthreads();
    }
    float* Sf = &Scb[0][0];
    {
#pragma clang fp contract(off)
        const int r = tid >> 3, j0 = tid & 7;
        int grow = m_base + r; if (grow >= NTEST) grow = NTEST - 1;
        const float* tp = test_x + (size_t)grow * DIM;
        const float ts = np_sq512(tp);
        for (int jj = j0; jj < 64; jj += 8) {
            const int idx = topI[r][jj];
            const float* xp = train_x + (size_t)idx * DIM;
            const float trsv = np_sq512(xp);
            const float dt = np_dot512(tp, xp);
            const float T = ts + trsv;
            const float w = 2.0f * dt;
            Sf[r * 64 + jj] = T - w;
        }
    }
    __syncthreads();
    int* sel = (int*)&topD[0][0];
    if (tid < FM_TILE) {
        const int r = tid;
        unsigned long long used = 0ULL;
        for (int p = 0; p < KNN; ++p) {
            float bv = FLT_MAX; int bj = 0; int bidx = 0x7fffffff;
            for (int j = 0; j < 64; ++j) {
                if (used & (1ULL << j)) continue;
                const float v = Sf[r * 64 + j];
                const int idv = topI[r][j];
                if (v < bv || (v == bv && idv < bidx)) { bv = v; bj = j; bidx = idv; }
            }
            used |= (1ULL << bj);
            sel[r * KNN + p] = bidx;
        }
    }
    __syncthreads();
    const int r = tid >> 3, c0 = (tid & 7) * 8;
    const int grow = m_base + r;
    if (grow < NTEST) {
        float s0=0,s1=0,s2=0,s3=0,s4=0,s5=0,s6=0,s7=0;
        for (int n = 0; n < KNN; ++n) {
            const float* yp = train_y + (size_t)sel[r * KNN + n] * NCOMP + c0;
            const float4 y0 = *(const float4*)yp;
            const float4 y1 = *(const float4*)(yp + 4);
            s0+=y0.x; s1+=y0.y; s2+=y0.z; s3+=y0.w;
            s4+=y1.x; s5+=y1.y; s6+=y1.z; s7+=y1.w;
        }
        const float inv = 1.0f / KNN;
        float* op = out + (size_t)grow * NCOMP + c0;
        *(float4*)op       = make_float4(s0*inv, s1*inv, s2*inv, s3*inv);
        *(float4*)(op + 4) = make_float4(s4*inv, s5*inv, s6*inv, s7*inv);
    }
}

// ======================= launcher =======================
extern "C" void kernel_launch(void* const* d_in, const int* in_sizes, int n_in,
                              void* d_out, int out_size, void* d_ws, size_t ws_size,
                              hipStream_t stream) {
    const float* train_x = (const float*)d_in[0];
    const float* train_y = (const float*)d_in[1];
    const float* test_x  = (const float*)d_in[2];
    float* out = (float*)d_out;

    if (ws_size < WS_NEED) {
        // not enough scratch for the staged pipeline -> verified round-3 kernel
        knn_fallback<<<(NTEST + FM_TILE - 1) / FM_TILE, 256, 0, stream>>>(
            train_x, train_y, test_x, out);
        return;
    }

    char* ws = (char*)d_ws;
    unsigned short* train_bf = (unsigned short*)(ws + OFF_TRAINBF);
    unsigned short* test_bf  = (unsigned short*)(ws + OFF_TESTBF);
    float*  trs      = (float*)(ws + OFF_TRS);
    float*  np_trs   = (float*)(ws + OFF_NPTRS);
    float*  np_tests = (float*)(ws + OFF_NPTESTS);
    float2* cand     = (float2*)(ws + OFF_CAND);
    int*    cut      = (int*)(ws + OFF_CUT);
    float*  d2       = (float*)(ws + OFF_D2);

    prep_convert<<<(NTRAIN + NTEST) / 4, 256, 0, stream>>>(train_x, test_x, train_bf, test_bf, trs);
    prep_npnorm<<<(NTRAIN + NTEST + 255) / 256, 256, 0, stream>>>(train_x, test_x, np_trs, np_tests);
    stageA<<<MTILES * NSEG, 256, 0, stream>>>(train_bf, test_bf, trs, cand);
    cut48<<<NTEST / 4, 256, 0, stream>>>(cand, cut);
    npd2_kernel<<<(NTEST * KCAND + 255) / 256, 256, 0, stream>>>(train_x, test_x, np_trs, np_tests, cut, d2);
    select_out<<<NTEST / 4, 256, 0, stream>>>(train_y, cut, d2, out);
}

// Round 5
// 1088.063 us; speedup vs baseline: 38.7926x; 2.2669x over previous
//
#include <hip/hip_runtime.h>
#include <cfloat>

#define NTRAIN 40000
#define NTEST  10000
#define DIM    512
#define NCOMP  64
#define KNN    32

// ---------------- stage-A geometry ----------------
#define NSEG   8
#define SEGC   (NTRAIN / NSEG)          // 5000 train cols per segment
#define BMT    64                        // test rows per WG
#define BNT    128                       // train cols per WG
#define BK     64
#define NTILES ((SEGC + BNT - 1) / BNT)  // 40
#define MTILES ((NTEST + BMT - 1) / BMT) // 157
#define LSEL   8                         // per-(row,bucket) register list length
#define DUMP   24                        // per-(row,seg) merged candidates dumped
#define KCAND  48                        // candidates re-ranked exactly per row

typedef __bf16 bf16x8 __attribute__((ext_vector_type(8)));
typedef float  f32x4  __attribute__((ext_vector_type(4)));
typedef unsigned short u16x8 __attribute__((ext_vector_type(8)));

// ---------------- workspace layout (bytes) ----------------
#define OFF_TRAINBF 0ULL                 // 40000*512*2 = 40,960,000
#define OFF_TESTBF  40960000ULL          // 10000*512*2 = 10,240,000
#define OFF_TRS     51200000ULL          // 40000*4
#define OFF_NPTRS   51360000ULL          // 40000*4
#define OFF_NPTESTS 51520000ULL          // 10000*4
#define OFF_CAND    51560448ULL          // 10000*8*24*4 = 7,680,000
#define OFF_CUT     59240448ULL          // 10000*48*4 = 1,920,000
#define OFF_D2      61160448ULL          // 10000*48*4 = 1,920,000
#define WS_NEED     63080448ULL

// ---------------------------------------------------------------------------
// np-f32 emulation of the harness reference (verified passing rounds 3-4):
//   norms = numpy pairwise sum (128-blocks, 8 accumulators)
//   dot   = sequential f32 FMA chain (BLAS microkernel accumulation order)
//   d2    = f32( f32(ts + trs) - 2*dot ), no FMA contraction
// ---------------------------------------------------------------------------
__device__ __forceinline__ float np_block128_sq(const float* __restrict__ q) {
#pragma clang fp contract(off)
    float r0 = q[0]*q[0], r1 = q[1]*q[1], r2 = q[2]*q[2], r3 = q[3]*q[3];
    float r4 = q[4]*q[4], r5 = q[5]*q[5], r6 = q[6]*q[6], r7 = q[7]*q[7];
    #pragma unroll
    for (int i = 8; i < 128; i += 8) {
        r0 += q[i+0]*q[i+0];
        r1 += q[i+1]*q[i+1];
        r2 += q[i+2]*q[i+2];
        r3 += q[i+3]*q[i+3];
        r4 += q[i+4]*q[i+4];
        r5 += q[i+5]*q[i+5];
        r6 += q[i+6]*q[i+6];
        r7 += q[i+7]*q[i+7];
    }
    return ((r0 + r1) + (r2 + r3)) + ((r4 + r5) + (r6 + r7));
}

__device__ __forceinline__ float np_sq512(const float* __restrict__ q) {
#pragma clang fp contract(off)
    const float b0 = np_block128_sq(q);
    const float b1 = np_block128_sq(q + 128);
    const float b2 = np_block128_sq(q + 256);
    const float b3 = np_block128_sq(q + 384);
    return (b0 + b1) + (b2 + b3);
}

__device__ __forceinline__ float np_dot512(const float* __restrict__ t,
                                           const float* __restrict__ x) {
    float acc = 0.f;
    for (int k = 0; k < DIM; k += 4) {
        const float4 tv = *(const float4*)(t + k);
        const float4 xv = *(const float4*)(x + k);
        acc = fmaf(tv.x, xv.x, acc);
        acc = fmaf(tv.y, xv.y, acc);
        acc = fmaf(tv.z, xv.z, acc);
        acc = fmaf(tv.w, xv.w, acc);
    }
    return acc;
}

__device__ __forceinline__ unsigned short f32_to_bf16_rne(float f) {
    unsigned int u = __float_as_uint(f);
    u += 0x7fffu + ((u >> 16) & 1u);
    return (unsigned short)(u >> 16);
}

__device__ __forceinline__ void global_load_lds16(const void* g, void* l) {
    __builtin_amdgcn_global_load_lds(
        (const __attribute__((address_space(1))) void*)g,
        (__attribute__((address_space(3))) void*)l, 16, 0, 0);
}

// sorted ascending 8-list insert (u32 keys)
__device__ __forceinline__ void kinsert(unsigned key, unsigned (&l)[LSEL]) {
    if (key < l[LSEL - 1]) {
        #pragma unroll
        for (int p = LSEL - 1; p >= 1; --p) {
            const bool up = key < l[p - 1];
            const unsigned nv = up ? l[p - 1] : key;
            if (key < l[p]) l[p] = nv;
        }
        if (key < l[0]) l[0] = key;
    }
}

// ======================= K0a: f32 -> bf16 + approx train norms =======================
__global__ void prep_convert(const float* __restrict__ train_x,
                             const float* __restrict__ test_x,
                             unsigned short* __restrict__ train_bf,
                             unsigned short* __restrict__ test_bf,
                             float* __restrict__ trs)
{
    const int wid = threadIdx.x >> 6, lane = threadIdx.x & 63;
    const int row = blockIdx.x * 4 + wid;              // 0..49999
    if (row >= NTRAIN + NTEST) return;
    const bool is_train = row < NTRAIN;
    const float* src = is_train ? (train_x + (size_t)row * DIM)
                                : (test_x + (size_t)(row - NTRAIN) * DIM);
    unsigned short* dst = is_train ? (train_bf + (size_t)row * DIM)
                                   : (test_bf + (size_t)(row - NTRAIN) * DIM);
    const float4 v0 = *(const float4*)(src + lane * 8);
    const float4 v1 = *(const float4*)(src + lane * 8 + 4);
    const float f[8] = {v0.x, v0.y, v0.z, v0.w, v1.x, v1.y, v1.z, v1.w};
    u16x8 o;
    float ss = 0.f;
    #pragma unroll
    for (int j = 0; j < 8; ++j) {
        o[j] = f32_to_bf16_rne(f[j]);
        ss += f[j] * f[j];
    }
    *(u16x8*)(dst + lane * 8) = o;
    if (is_train) {
        #pragma unroll
        for (int d = 1; d < 64; d <<= 1) ss += __shfl_xor(ss, d);
        if (lane == 0) trs[row] = ss;
    }
}

// ======================= K0b: exact np norms =======================
__global__ void prep_npnorm(const float* __restrict__ train_x,
                            const float* __restrict__ test_x,
                            float* __restrict__ np_trs,
                            float* __restrict__ np_tests)
{
    const int t = blockIdx.x * 256 + threadIdx.x;
    if (t < NTRAIN)                np_trs[t] = np_sq512(train_x + (size_t)t * DIM);
    else if (t < NTRAIN + NTEST)   np_tests[t - NTRAIN] = np_sq512(test_x + (size_t)(t - NTRAIN) * DIM);
}

// ======================= K1: MFMA candidate generation (swapped operands) =======================
// WG: 64 test rows x 128 train cols, BK=64, K=512. 4 waves, wave w owns train
// cols [w*32, w*32+32). mfma(A=train, B=test) => per lane: test rows {16j+l15},
// train cols {w*32+16i+4*l4+r}. Selection fully in registers: 4 sorted 8-lists
// of u32 keys (monotone-f32 top-19 bits | 13-bit seg-local col idx).
// seg = blockIdx & 7 pins each train segment to one XCD (L2 locality).
__global__ __launch_bounds__(256, 3)
void stageA(const unsigned short* __restrict__ train_bf,
            const unsigned short* __restrict__ test_bf,
            const float* __restrict__ trs,
            unsigned* __restrict__ cand)
{
    __shared__ unsigned short Ab[BMT * BK];   // 8 KB  (test tile, granule-swizzled)
    __shared__ unsigned short Bb[BNT * BK];   // 16 KB (train tile)
    __shared__ float colTrs[BNT];             // 512 B
    __shared__ unsigned Mg[16][16][LSEL];     // 8 KB  (end-of-WG merge buffer)

    const int tid  = threadIdx.x;
    const int wid  = tid >> 6;
    const int lane = tid & 63;
    const int l15 = lane & 15, l4 = lane >> 4;
    const int wcol0 = wid * 32;

    const int seg    = blockIdx.x & 7;
    const int m_base = (blockIdx.x >> 3) * BMT;
    const int seg0   = seg * SEGC;

    unsigned lst[4][LSEL];
    #pragma unroll
    for (int j = 0; j < 4; ++j)
        #pragma unroll
        for (int s = 0; s < LSEL; ++s) lst[j][s] = 0xFFFFFFFFu;

    for (int tile = 0; tile < NTILES; ++tile) {
        const int n_base = tile * BNT;

        float trsv = 0.f;
        if (tid < BNT) {
            int c = n_base + tid; if (c > SEGC - 1) c = SEGC - 1;
            trsv = trs[seg0 + c];
        }

        f32x4 acc[2][4];
        #pragma unroll
        for (int i = 0; i < 2; ++i)
            #pragma unroll
            for (int j = 0; j < 4; ++j) acc[i][j] = (f32x4){0.f, 0.f, 0.f, 0.f};

        float ctrs[8];

        for (int kc = 0; kc < DIM / BK; ++kc) {
            const int k_base = kc * BK;
            __syncthreads();                       // previous LDS consumers done
            #pragma unroll
            for (int s = 0; s < 2; ++s) {          // A(test): 512 granules
                const int d   = wid * 128 + s * 64 + lane;
                const int row = d >> 3;
                const int g   = (d & 7) ^ (row & 7);
                int grow = m_base + row; if (grow > NTEST - 1) grow = NTEST - 1;
                global_load_lds16(test_bf + (size_t)grow * DIM + k_base + g * 8,
                                  &Ab[(wid * 128 + s * 64) * 8]);
            }
            #pragma unroll
            for (int s = 0; s < 4; ++s) {          // B(train): 1024 granules
                const int d   = wid * 256 + s * 64 + lane;
                const int row = d >> 3;
                const int g   = (d & 7) ^ (row & 7);
                int cis = n_base + row; if (cis > SEGC - 1) cis = SEGC - 1;
                global_load_lds16(train_bf + (size_t)(seg0 + cis) * DIM + k_base + g * 8,
                                  &Bb[(wid * 256 + s * 64) * 8]);
            }
            if (kc == 0 && tid < BNT) colTrs[tid] = trsv;
            __syncthreads();                       // vmcnt(0) drain + barrier
            if (kc == 0) {
                #pragma unroll
                for (int i = 0; i < 2; ++i)
                    #pragma unroll
                    for (int r = 0; r < 4; ++r)
                        ctrs[i * 4 + r] = colTrs[wcol0 + i * 16 + l4 * 4 + r];
            }
            #pragma unroll
            for (int h = 0; h < 2; ++h) {          // two K=32 halves
                bf16x8 bF[4];
                #pragma unroll
                for (int j = 0; j < 4; ++j) {
                    const int trow = j * 16 + l15;
                    bF[j] = *(const bf16x8*)&Ab[(trow * 8 + ((h * 4 + l4) ^ (trow & 7))) * 8];
                }
                #pragma unroll
                for (int i = 0; i < 2; ++i) {
                    const int tcol = wcol0 + i * 16 + l15;
                    const bf16x8 aF = *(const bf16x8*)&Bb[(tcol * 8 + ((h * 4 + l4) ^ (tcol & 7))) * 8];
                    #pragma unroll
                    for (int j = 0; j < 4; ++j)
                        acc[i][j] = __builtin_amdgcn_mfma_f32_16x16x32_bf16(
                            aF, bF[j], acc[i][j], 0, 0, 0);
                }
            }
        }

        // -------- in-register selection (no barriers, no LDS) --------
        #pragma unroll
        for (int j = 0; j < 4; ++j) {
            #pragma unroll
            for (int i = 0; i < 2; ++i) {
                #pragma unroll
                for (int r = 0; r < 4; ++r) {
                    const int lidx = n_base + wcol0 + i * 16 + l4 * 4 + r;
                    if (lidx < SEGC) {
                        const float s = fmaf(-2.f, acc[i][j][r], ctrs[i * 4 + r]);
                        const unsigned u = __float_as_uint(s);
                        const unsigned mono = (u >> 31) ? ~u : (u | 0x80000000u);
                        const unsigned key = (mono & 0xFFFFE000u) | (unsigned)lidx;
                        kinsert(key, lst[j]);
                    }
                }
            }
        }
    }

    // -------- end-of-WG merge: per row, 16 buckets x 8 -> top-24 dump --------
    #pragma unroll
    for (int c = 0; c < 4; ++c) {                  // chunk c == list j == rows 16c..16c+15
        __syncthreads();
        #pragma unroll
        for (int s = 0; s < LSEL; ++s) Mg[l15][wid * 4 + l4][s] = lst[c][s];
        __syncthreads();
        const int mrow = tid >> 4;                 // 0..15 (row within chunk)
        const int mb   = tid & 15;                 // my bucket
        unsigned mine[LSEL];
        #pragma unroll
        for (int s = 0; s < LSEL; ++s) mine[s] = Mg[mrow][mb][s];
        int rank[LSEL];
        #pragma unroll
        for (int s = 0; s < LSEL; ++s) rank[s] = 0;
        for (int ob = 0; ob < 16; ++ob) {
            #pragma unroll
            for (int os = 0; os < LSEL; ++os) {
                const unsigned ok = Mg[mrow][ob][os];
                #pragma unroll
                for (int s = 0; s < LSEL; ++s) rank[s] += (ok < mine[s]) ? 1 : 0;
            }
        }
        const int grow = m_base + c * 16 + mrow;
        if (grow < NTEST) {
            #pragma unroll
            for (int s = 0; s < LSEL; ++s)
                if (rank[s] < DUMP)
                    cand[((size_t)grow * NSEG + seg) * DUMP + rank[s]] = mine[s];
        }
    }
}

// ======================= K2: cut 192 -> 48 by approx key =======================
__global__ void cut48k(const unsigned* __restrict__ cand, int* __restrict__ cut)
{
    __shared__ unsigned long long C[8][NSEG * DUMP];   // 8 x 192 x 8B = 12 KB
    const int tid = threadIdx.x;
    const int rw = tid >> 5;                           // row within WG (8 rows)
    const int l32 = tid & 31;
    const int row = blockIdx.x * 8 + rw;               // grid*8 == NTEST exactly
    #pragma unroll
    for (int t = 0; t < 6; ++t) {
        const int e = l32 + t * 32;
        const unsigned key = cand[(size_t)row * (NSEG * DUMP) + e];
        const int sg = e / DUMP;
        const unsigned gidx = (unsigned)(sg * SEGC) + (key & 0x1FFFu);
        C[rw][e] = ((unsigned long long)(key >> 13) << 32) | gidx;
    }
    __syncthreads();
    #pragma unroll
    for (int t = 0; t < 6; ++t) {
        const int e = l32 + t * 32;
        const unsigned long long mk = C[rw][e];
        int rank = 0;
        for (int o = 0; o < NSEG * DUMP; ++o) rank += (C[rw][o] < mk) ? 1 : 0;
        if (rank < KCAND) cut[(size_t)row * KCAND + rank] = (int)(mk & 0xFFFFFFFFULL);
    }
}

// ======================= K3: exact np-f32 d2 for 48 candidates =======================
__global__ void npd2_kernel(const float* __restrict__ train_x,
                            const float* __restrict__ test_x,
                            const float* __restrict__ np_trs,
                            const float* __restrict__ np_tests,
                            const int* __restrict__ cut,
                            float* __restrict__ d2)
{
#pragma clang fp contract(off)
    const int T = blockIdx.x * 256 + threadIdx.x;
    if (T >= NTEST * KCAND) return;
    const int row = T / KCAND;
    const int idx = cut[T];
    const float dt = np_dot512(test_x + (size_t)row * DIM, train_x + (size_t)idx * DIM);
    const float Tv = np_tests[row] + np_trs[idx];   // f32 round
    const float w  = 2.0f * dt;                     // exact
    d2[T] = Tv - w;                                 // f32 round, no contraction
}

// ======================= K4: top-32 select + label mean =======================
__global__ void select_out(const float* __restrict__ train_y,
                           const int* __restrict__ cut,
                           const float* __restrict__ d2,
                           float* __restrict__ out)
{
    __shared__ float D[4][KCAND];
    __shared__ int   I[4][KCAND];
    __shared__ int   S[4][KNN];
    const int wid = threadIdx.x >> 6, lane = threadIdx.x & 63;
    const int row = blockIdx.x * 4 + wid;        // grid*4 == NTEST exactly
    if (lane < KCAND) {
        D[wid][lane] = d2[(size_t)row * KCAND + lane];
        I[wid][lane] = cut[(size_t)row * KCAND + lane];
    }
    __syncthreads();
    if (lane < KCAND) {
        const float ms = D[wid][lane]; const int mi = I[wid][lane];
        int rank = 0;
        #pragma unroll
        for (int o = 0; o < KCAND; ++o)
            rank += (D[wid][o] < ms || (D[wid][o] == ms && I[wid][o] < mi)) ? 1 : 0;
        if (rank < KNN) S[wid][rank] = mi;       // (dist, idx) order == lax.top_k
    }
    __syncthreads();
    float s = 0.f;
    #pragma unroll
    for (int n = 0; n < KNN; ++n)
        s += train_y[(size_t)S[wid][n] * NCOMP + lane];
    out[(size_t)row * NCOMP + lane] = s * (1.0f / KNN);
}

// ======================= fallback: round-3 monolithic kernel =======================
#define FM_TILE 32
#define FN_TILE 256
#define FK_CHUNK 16
__global__ __launch_bounds__(256, 2)
void knn_fallback(const float* __restrict__ train_x,
                  const float* __restrict__ train_y,
                  const float* __restrict__ test_x,
                  float* __restrict__ out)
{
    __shared__ float As[FK_CHUNK][FM_TILE];
    __shared__ float Bs[FK_CHUNK][FN_TILE];
    __shared__ float Scb[FM_TILE][FN_TILE + 1];
    __shared__ float colSq[FN_TILE];
    __shared__ float topD[FM_TILE][64];
    __shared__ int   topI[FM_TILE][64];

    const int tid    = threadIdx.x;
    const int m_base = blockIdx.x * FM_TILE;
    const int tx     = tid & 31;
    const int ty     = tid >> 5;

    for (int i = tid; i < FM_TILE * 64; i += 256) {
        (&topD[0][0])[i] = FLT_MAX;
        (&topI[0][0])[i] = 0;
    }
    float rowMax = FLT_MAX;
    const int a_row  = tid >> 2;
    const int a_k    = (tid & 3) * 4;
    const int a_grow = (m_base + a_row < NTEST) ? (m_base + a_row) : (NTEST - 1);

    for (int n_base = 0; n_base < NTRAIN; n_base += FN_TILE) {
        float accf[4][8];
        #pragma unroll
        for (int i = 0; i < 4; ++i)
            #pragma unroll
            for (int j = 0; j < 8; ++j) accf[i][j] = 0.f;
        int b_row = n_base + tid;
        if (b_row >= NTRAIN) b_row = NTRAIN - 1;
        const float* bp = train_x + (size_t)b_row * DIM;
        float sq_acc = 0.f;
        for (int k_base = 0; k_base < DIM; k_base += FK_CHUNK) {
            __syncthreads();
            if (tid < 128) {
                const float4 v = *(const float4*)(test_x + (size_t)a_grow * DIM + k_base + a_k);
                As[a_k + 0][a_row] = v.x; As[a_k + 1][a_row] = v.y;
                As[a_k + 2][a_row] = v.z; As[a_k + 3][a_row] = v.w;
            }
            {
                const float4* tp = (const float4*)(bp + k_base);
                const float4 v0 = tp[0], v1 = tp[1], v2 = tp[2], v3 = tp[3];
                Bs[0][tid]=v0.x; Bs[1][tid]=v0.y; Bs[2][tid]=v0.z; Bs[3][tid]=v0.w;
                Bs[4][tid]=v1.x; Bs[5][tid]=v1.y; Bs[6][tid]=v1.z; Bs[7][tid]=v1.w;
                Bs[8][tid]=v2.x; Bs[9][tid]=v2.y; Bs[10][tid]=v2.z; Bs[11][tid]=v2.w;
                Bs[12][tid]=v3.x; Bs[13][tid]=v3.y; Bs[14][tid]=v3.z; Bs[15][tid]=v3.w;
                sq_acc += v0.x*v0.x+v0.y*v0.y+v0.z*v0.z+v0.w*v0.w
                        + v1.x*v1.x+v1.y*v1.y+v1.z*v1.z+v1.w*v1.w
                        + v2.x*v2.x+v2.y*v2.y+v2.z*v2.z+v2.w*v2.w
                        + v3.x*v3.x+v3.y*v3.y+v3.z*v3.z+v3.w*v3.w;
            }
            __syncthreads();
            #pragma unroll
            for (int k = 0; k < FK_CHUNK; ++k) {
                const float4 av  = *(const float4*)&As[k][ty * 4];
                const float4 bv0 = *(const float4*)&Bs[k][tx * 8];
                const float4 bv1 = *(const float4*)&Bs[k][tx * 8 + 4];
                const float a[4] = {av.x, av.y, av.z, av.w};
                const float b[8] = {bv0.x, bv0.y, bv0.z, bv0.w, bv1.x, bv1.y, bv1.z, bv1.w};
                #pragma unroll
                for (int i = 0; i < 4; ++i)
                    #pragma unroll
                    for (int j = 0; j < 8; ++j)
                        accf[i][j] = fmaf(a[i], b[j], accf[i][j]);
            }
        }
        colSq[tid] = sq_acc;
        __syncthreads();
        #pragma unroll
        for (int i = 0; i < 4; ++i)
            #pragma unroll
            for (int j = 0; j < 8; ++j) {
                const int c = tx * 8 + j;
                const int gcol = n_base + c;
                Scb[ty * 4 + i][c] = (gcol < NTRAIN) ? (colSq[c] - 2.f * accf[i][j]) : FLT_MAX;
            }
        __syncthreads();
        if (tid < FM_TILE) {
            float rmax = rowMax;
            for (int c = 0; c < FN_TILE; ++c) {
                const float s = Scb[tid][c];
                if (s < rmax) {
                    int bi = 0; float bv = topD[tid][0]; int bidx = topI[tid][0];
                    #pragma unroll
                    for (int i = 1; i < 64; ++i) {
                        const float v = topD[tid][i]; const int idv = topI[tid][i];
                        if (v > bv || (v == bv && idv > bidx)) { bv = v; bi = i; bidx = idv; }
                    }
                    topD[tid][bi] = s; topI[tid][bi] = n_base + c;
                    float nm = -FLT_MAX;
                    #pragma unroll
                    for (int i = 0; i < 64; ++i) nm = fmaxf(nm, topD[tid][i]);
                    rmax = nm;
                }
            }
            rowMax = rmax;
        }
        __syncthreads();
    }
    float* Sf = &Scb[0][0];
    {
#pragma clang fp contract(off)
        const int r = tid >> 3, j0 = tid & 7;
        int grow = m_base + r; if (grow >= NTEST) grow = NTEST - 1;
        const float* tp = test_x + (size_t)grow * DIM;
        const float ts = np_sq512(tp);
        for (int jj = j0; jj < 64; jj += 8) {
            const int idx = topI[r][jj];
            const float* xp = train_x + (size_t)idx * DIM;
            const float trsv = np_sq512(xp);
            const float dt = np_dot512(tp, xp);
            const float T = ts + trsv;
            const float w = 2.0f * dt;
            Sf[r * 64 + jj] = T - w;
        }
    }
    __syncthreads();
    int* sel = (int*)&topD[0][0];
    if (tid < FM_TILE) {
        const int r = tid;
        unsigned long long used = 0ULL;
        for (int p = 0; p < KNN; ++p) {
            float bv = FLT_MAX; int bj = 0; int bidx = 0x7fffffff;
            for (int j = 0; j < 64; ++j) {
                if (used & (1ULL << j)) continue;
                const float v = Sf[r * 64 + j];
                const int idv = topI[r][j];
                if (v < bv || (v == bv && idv < bidx)) { bv = v; bj = j; bidx = idv; }
            }
            used |= (1ULL << bj);
            sel[r * KNN + p] = bidx;
        }
    }
    __syncthreads();
    const int r = tid >> 3, c0 = (tid & 7) * 8;
    const int grow = m_base + r;
    if (grow < NTEST) {
        float s0=0,s1=0,s2=0,s3=0,s4=0,s5=0,s6=0,s7=0;
        for (int n = 0; n < KNN; ++n) {
            const float* yp = train_y + (size_t)sel[r * KNN + n] * NCOMP + c0;
            const float4 y0 = *(const float4*)yp;
            const float4 y1 = *(const float4*)(yp + 4);
            s0+=y0.x; s1+=y0.y; s2+=y0.z; s3+=y0.w;
            s4+=y1.x; s5+=y1.y; s6+=y1.z; s7+=y1.w;
        }
        const float inv = 1.0f / KNN;
        float* op = out + (size_t)grow * NCOMP + c0;
        *(float4*)op       = make_float4(s0*inv, s1*inv, s2*inv, s3*inv);
        *(float4*)(op + 4) = make_float4(s4*inv, s5*inv, s6*inv, s7*inv);
    }
}

// ======================= launcher =======================
extern "C" void kernel_launch(void* const* d_in, const int* in_sizes, int n_in,
                              void* d_out, int out_size, void* d_ws, size_t ws_size,
                              hipStream_t stream) {
    const float* train_x = (const float*)d_in[0];
    const float* train_y = (const float*)d_in[1];
    const float* test_x  = (const float*)d_in[2];
    float* out = (float*)d_out;

    if (ws_size < WS_NEED) {
        knn_fallback<<<(NTEST + FM_TILE - 1) / FM_TILE, 256, 0, stream>>>(
            train_x, train_y, test_x, out);
        return;
    }

    char* ws = (char*)d_ws;
    unsigned short* train_bf = (unsigned short*)(ws + OFF_TRAINBF);
    unsigned short* test_bf  = (unsigned short*)(ws + OFF_TESTBF);
    float*  trs      = (float*)(ws + OFF_TRS);
    float*  np_trs   = (float*)(ws + OFF_NPTRS);
    float*  np_tests = (float*)(ws + OFF_NPTESTS);
    unsigned* cand   = (unsigned*)(ws + OFF_CAND);
    int*    cut      = (int*)(ws + OFF_CUT);
    float*  d2       = (float*)(ws + OFF_D2);

    prep_convert<<<(NTRAIN + NTEST) / 4, 256, 0, stream>>>(train_x, test_x, train_bf, test_bf, trs);
    prep_npnorm<<<(NTRAIN + NTEST + 255) / 256, 256, 0, stream>>>(train_x, test_x, np_trs, np_tests);
    stageA<<<MTILES * NSEG, 256, 0, stream>>>(train_bf, test_bf, trs, cand);
    cut48k<<<NTEST / 8, 256, 0, stream>>>(cand, cut);
    npd2_kernel<<<(NTEST * KCAND + 255) / 256, 256, 0, stream>>>(train_x, test_x, np_trs, np_tests, cut, d2);
    select_out<<<NTEST / 4, 256, 0, stream>>>(train_y, cut, d2, out);
}